// Round 1
// baseline (264.844 us; speedup 1.0000x reference)
//
#include <hip/hip_runtime.h>
#include <math.h>

#define D_X      1024
#define D_TEXT   768
#define FDIM     1792
#define BATCH    256
#define M_EXP    16
#define HW_TOT   1024   // 32*32

// Output layout (flat f32): gates[4096] | moe_loss[1] | probs[4096] | top_idx[512]
#define OUT_GATES 0
#define OUT_LOSS  4096
#define OUT_PROBS 4097
#define OUT_IDX   8193

// ---------------------------------------------------------------------------
// Kernel 1: mean-pool x (B, 1024, 32, 32) -> fused[:, :1024]
// one wave per (b, c) row of 1024 contiguous floats
// ---------------------------------------------------------------------------
__global__ __launch_bounds__(256) void pool_kernel(const float* __restrict__ x,
                                                   float* __restrict__ fused) {
    const int gtid = blockIdx.x * 256 + threadIdx.x;
    const int wave = gtid >> 6;            // row id in [0, BATCH*D_X)
    const int lane = gtid & 63;
    const float4* xr = reinterpret_cast<const float4*>(x + (size_t)wave * HW_TOT);
    float s = 0.0f;
#pragma unroll
    for (int k = 0; k < 4; ++k) {
        float4 v = xr[k * 64 + lane];
        s += v.x + v.y + v.z + v.w;
    }
#pragma unroll
    for (int off = 32; off > 0; off >>= 1) s += __shfl_xor(s, off, 64);
    if (lane == 0) {
        const int b = wave >> 10;          // / 1024
        const int c = wave & 1023;
        fused[(size_t)b * FDIM + c] = s * (1.0f / 1024.0f);
    }
}

// ---------------------------------------------------------------------------
// Kernel 2: copy degraded (256, 768) -> fused[:, 1024:]
// ---------------------------------------------------------------------------
__global__ __launch_bounds__(256) void copy_deg_kernel(const float* __restrict__ deg,
                                                       float* __restrict__ fused) {
    const int tid = blockIdx.x * 256 + threadIdx.x;   // float4 index, 49152 total
    if (tid >= BATCH * (D_TEXT / 4)) return;
    const int b  = tid / (D_TEXT / 4);
    const int j4 = tid % (D_TEXT / 4);
    const float4 v = reinterpret_cast<const float4*>(deg)[tid];
    reinterpret_cast<float4*>(fused)[(size_t)b * (FDIM / 4) + (D_X / 4) + j4] = v;
}

// ---------------------------------------------------------------------------
// Kernel 3: act = gelu(fused @ W + bias), exact gelu
// A: (256, 1792) row-major; W: (1792, 1792) row-major (k, n)
// tile 32(M) x 64(N), BK=32, 256 threads, per-thread 2x4
// ---------------------------------------------------------------------------
#define BM 32
#define BN 64
#define BK 32

__global__ __launch_bounds__(256) void gemm_gelu_kernel(const float* __restrict__ A,
                                                        const float* __restrict__ W,
                                                        const float* __restrict__ bias,
                                                        float* __restrict__ C) {
    __shared__ float As[BK][BM];   // transposed: As[k][m]
    __shared__ float Ws[BK][BN];

    const int tid = threadIdx.x;
    const int tx = tid & 15;       // 16 col groups of 4
    const int ty = tid >> 4;       // 16 row groups of 2
    const int m0 = blockIdx.x * BM;
    const int n0 = blockIdx.y * BN;

    float acc[2][4] = {};

    for (int k0 = 0; k0 < FDIM; k0 += BK) {
        // A tile: 32 rows x 32 k = 256 float4, 1 per thread (coalesced)
        {
            const int row = tid >> 3;            // 0..31
            const int kk4 = (tid & 7) * 4;       // 0,4,..,28
            float4 v = *reinterpret_cast<const float4*>(A + (size_t)(m0 + row) * FDIM + k0 + kk4);
            As[kk4 + 0][row] = v.x;
            As[kk4 + 1][row] = v.y;
            As[kk4 + 2][row] = v.z;
            As[kk4 + 3][row] = v.w;
        }
        // W tile: 32 k x 64 n = 512 float4, 2 per thread (coalesced)
#pragma unroll
        for (int i = 0; i < 2; ++i) {
            const int id = i * 256 + tid;
            const int kk = id >> 4;              // 0..31
            const int n4 = (id & 15) * 4;        // 0..60
            *reinterpret_cast<float4*>(&Ws[kk][n4]) =
                *reinterpret_cast<const float4*>(W + (size_t)(k0 + kk) * FDIM + n0 + n4);
        }
        __syncthreads();

#pragma unroll
        for (int kk = 0; kk < BK; ++kk) {
            const float2 a = *reinterpret_cast<const float2*>(&As[kk][ty * 2]);
            const float4 w = *reinterpret_cast<const float4*>(&Ws[kk][tx * 4]);
            const float av[2] = {a.x, a.y};
            const float wv[4] = {w.x, w.y, w.z, w.w};
#pragma unroll
            for (int i = 0; i < 2; ++i)
#pragma unroll
                for (int j = 0; j < 4; ++j)
                    acc[i][j] = fmaf(av[i], wv[j], acc[i][j]);
        }
        __syncthreads();
    }

#pragma unroll
    for (int i = 0; i < 2; ++i) {
        const int m = m0 + ty * 2 + i;
#pragma unroll
        for (int j = 0; j < 4; ++j) {
            const int n = n0 + tx * 4 + j;
            const float v = acc[i][j] + bias[n];
            const float g = v * 0.5f * (1.0f + erff(v * 0.70710678118654752440f));
            C[(size_t)m * FDIM + n] = g;
        }
    }
}

// ---------------------------------------------------------------------------
// Kernel 4: logits = act @ w_gate (1792x16); softmax; top-2 routing
// one block (256 threads) per batch row
// ---------------------------------------------------------------------------
__global__ __launch_bounds__(256) void gate_kernel(const float* __restrict__ act,
                                                   const float* __restrict__ wg,
                                                   float* __restrict__ out) {
    const int b = blockIdx.x;
    const int tid = threadIdx.x;

    float p[M_EXP];
#pragma unroll
    for (int m = 0; m < M_EXP; ++m) p[m] = 0.0f;

    for (int k = tid; k < FDIM; k += 256) {
        const float a = act[(size_t)b * FDIM + k];
        const float4* wr = reinterpret_cast<const float4*>(wg + (size_t)k * M_EXP);
#pragma unroll
        for (int q = 0; q < 4; ++q) {
            const float4 w = wr[q];
            p[q * 4 + 0] = fmaf(a, w.x, p[q * 4 + 0]);
            p[q * 4 + 1] = fmaf(a, w.y, p[q * 4 + 1]);
            p[q * 4 + 2] = fmaf(a, w.z, p[q * 4 + 2]);
            p[q * 4 + 3] = fmaf(a, w.w, p[q * 4 + 3]);
        }
    }

    // wave reduce (width 64)
#pragma unroll
    for (int off = 32; off > 0; off >>= 1) {
#pragma unroll
        for (int m = 0; m < M_EXP; ++m) p[m] += __shfl_xor(p[m], off, 64);
    }

    __shared__ float red[4][M_EXP];
    const int wid = tid >> 6;
    const int lane = tid & 63;
    if (lane == 0) {
#pragma unroll
        for (int m = 0; m < M_EXP; ++m) red[wid][m] = p[m];
    }
    __syncthreads();

    if (tid == 0) {
        float l[M_EXP];
#pragma unroll
        for (int m = 0; m < M_EXP; ++m)
            l[m] = red[0][m] + red[1][m] + red[2][m] + red[3][m];

        // softmax over all 16 (probs_for_mi)
        float mx = l[0];
#pragma unroll
        for (int m = 1; m < M_EXP; ++m) mx = fmaxf(mx, l[m]);
        float e[M_EXP], s = 0.0f;
#pragma unroll
        for (int m = 0; m < M_EXP; ++m) { e[m] = expf(l[m] - mx); s += e[m]; }
        const float inv = 1.0f / s;
#pragma unroll
        for (int m = 0; m < M_EXP; ++m) out[OUT_PROBS + b * M_EXP + m] = e[m] * inv;

        // top-2 with earliest-index tie-break (matches lax.top_k ordering)
        int i0 = 0; float v0 = l[0];
#pragma unroll
        for (int m = 1; m < M_EXP; ++m) if (l[m] > v0) { v0 = l[m]; i0 = m; }
        int i1 = -1; float v1 = -INFINITY;
#pragma unroll
        for (int m = 0; m < M_EXP; ++m) if (m != i0 && l[m] > v1) { v1 = l[m]; i1 = m; }

        // softmax over [v0, v1] (v0 is the max)
        const float t = expf(v1 - v0);
        const float g0 = 1.0f / (1.0f + t);
        const float g1 = t * g0;

        // gates row: zeros then scatter top-2
#pragma unroll
        for (int m = 0; m < M_EXP; ++m) out[OUT_GATES + b * M_EXP + m] = 0.0f;
        out[OUT_GATES + b * M_EXP + i0] = g0;
        out[OUT_GATES + b * M_EXP + i1] = g1;

        // indices stored as float values
        out[OUT_IDX + b * 2 + 0] = (float)i0;
        out[OUT_IDX + b * 2 + 1] = (float)i1;

        if (b == 0) out[OUT_LOSS] = 0.0f;
    }
}

// ---------------------------------------------------------------------------
extern "C" void kernel_launch(void* const* d_in, const int* in_sizes, int n_in,
                              void* d_out, int out_size, void* d_ws, size_t ws_size,
                              hipStream_t stream) {
    const float* x        = (const float*)d_in[0];
    const float* degraded = (const float*)d_in[1];
    const float* w_fusion = (const float*)d_in[2];
    const float* b_fusion = (const float*)d_in[3];
    const float* w_gate   = (const float*)d_in[4];
    float* out = (float*)d_out;

    float* fused = (float*)d_ws;                        // 256*1792 f32
    float* actb  = fused + (size_t)BATCH * FDIM;        // 256*1792 f32

    // 1) pool: 262144 waves -> 65536 blocks of 256
    pool_kernel<<<(BATCH * D_X) / 4, 256, 0, stream>>>(x, fused);

    // 2) degraded copy: 49152 float4 -> 192 blocks
    copy_deg_kernel<<<192, 256, 0, stream>>>(degraded, fused);

    // 3) fusion GEMM + bias + exact gelu: grid (256/32, 1792/64) = (8, 28)
    gemm_gelu_kernel<<<dim3(BATCH / BM, FDIM / BN), 256, 0, stream>>>(fused, w_fusion, b_fusion, actb);

    // 4) gate: one block per row
    gate_kernel<<<BATCH, 256, 0, stream>>>(actb, w_gate, out);
}

// Round 2
// 250.053 us; speedup vs baseline: 1.0592x; 1.0592x over previous
//
#include <hip/hip_runtime.h>
#include <math.h>

#define D_X      1024
#define D_TEXT   768
#define FDIM     1792
#define BATCH    256
#define M_EXP    16
#define HW_TOT   1024   // 32*32

// Output layout (flat f32): gates[4096] | moe_loss[1] | probs[4096] | top_idx[512]
#define OUT_GATES 0
#define OUT_LOSS  4096
#define OUT_PROBS 4097
#define OUT_IDX   8193

#define NBLK_POOL (BATCH * D_X / 4)   // 65536
#define NBLK_COPY 192

// ---------------------------------------------------------------------------
// Kernel 1: mean-pool x (B,1024,32,32) -> fused[:, :1024]  (one wave per row)
//           + copy degraded (256,768) -> fused[:, 1024:]   (tail blocks)
// ---------------------------------------------------------------------------
__global__ __launch_bounds__(256) void pool_copy_kernel(const float* __restrict__ x,
                                                        const float* __restrict__ deg,
                                                        float* __restrict__ fused) {
    const int blk = blockIdx.x;
    if (blk < NBLK_POOL) {
        const int gtid = blk * 256 + threadIdx.x;
        const int row  = gtid >> 6;            // (b,c) id in [0, BATCH*D_X)
        const int lane = gtid & 63;
        const float4* xr = reinterpret_cast<const float4*>(x + (size_t)row * HW_TOT);
        float s = 0.0f;
#pragma unroll
        for (int k = 0; k < 4; ++k) {
            float4 v = xr[k * 64 + lane];
            s += v.x + v.y + v.z + v.w;
        }
#pragma unroll
        for (int off = 32; off > 0; off >>= 1) s += __shfl_xor(s, off, 64);
        if (lane == 0) {
            const int b = row >> 10;
            const int c = row & 1023;
            fused[(size_t)b * FDIM + c] = s * (1.0f / 1024.0f);
        }
    } else {
        const int tid = (blk - NBLK_POOL) * 256 + threadIdx.x;  // float4 id
        if (tid < BATCH * (D_TEXT / 4)) {
            const int b  = tid / (D_TEXT / 4);
            const int j4 = tid % (D_TEXT / 4);
            const float4 v = reinterpret_cast<const float4*>(deg)[tid];
            reinterpret_cast<float4*>(fused)[(size_t)b * (FDIM / 4) + (D_X / 4) + j4] = v;
        }
    }
}

// ---------------------------------------------------------------------------
// Kernel 2: act = gelu(fused @ W + bias) tile, then partial logits
//           part[nb][m][e] = sum_{n in block} act[m][n] * wg[n][e]
// A: (256,1792) rm; W: (1792,1792) rm (k,n); wg: (1792,16) rm
// tile 32(M) x 64(N), BK=64, 256 threads, per-thread 2x4, reg-staged dbuf LDS
// ---------------------------------------------------------------------------
#define BM 32
#define BN 64
#define BK 64
#define NITER (FDIM / BK)   // 28

#define LOADA(k0)                                                                     \
    pa0 = *reinterpret_cast<const float4*>(A + (size_t)(m0 + ar) * FDIM + (k0) + ak4);       \
    pa1 = *reinterpret_cast<const float4*>(A + (size_t)(m0 + ar + 16) * FDIM + (k0) + ak4);

#define LOADW(k0)                                                                     \
    pw0 = *reinterpret_cast<const float4*>(W + (size_t)((k0) + wr0) * FDIM + n0 + wc4);      \
    pw1 = *reinterpret_cast<const float4*>(W + (size_t)((k0) + wr0 + 16) * FDIM + n0 + wc4); \
    pw2 = *reinterpret_cast<const float4*>(W + (size_t)((k0) + wr0 + 32) * FDIM + n0 + wc4); \
    pw3 = *reinterpret_cast<const float4*>(W + (size_t)((k0) + wr0 + 48) * FDIM + n0 + wc4);

#define STOREA(buf)                                                                   \
    As[buf][ak4 + 0][ar] = pa0.x; As[buf][ak4 + 1][ar] = pa0.y;                       \
    As[buf][ak4 + 2][ar] = pa0.z; As[buf][ak4 + 3][ar] = pa0.w;                       \
    As[buf][ak4 + 0][ar + 16] = pa1.x; As[buf][ak4 + 1][ar + 16] = pa1.y;             \
    As[buf][ak4 + 2][ar + 16] = pa1.z; As[buf][ak4 + 3][ar + 16] = pa1.w;

#define STOREW(buf)                                                                   \
    *reinterpret_cast<float4*>(&Ws[buf][wr0][wc4])      = pw0;                        \
    *reinterpret_cast<float4*>(&Ws[buf][wr0 + 16][wc4]) = pw1;                        \
    *reinterpret_cast<float4*>(&Ws[buf][wr0 + 32][wc4]) = pw2;                        \
    *reinterpret_cast<float4*>(&Ws[buf][wr0 + 48][wc4]) = pw3;

__global__ __launch_bounds__(256) void gemm_gate_kernel(const float* __restrict__ A,
                                                        const float* __restrict__ W,
                                                        const float* __restrict__ bias,
                                                        const float* __restrict__ wg,
                                                        float* __restrict__ part) {
    __shared__ float As[2][BK][BM + 1];   // transposed [k][m], pad -> 2-way max
    __shared__ float Ws[2][BK][BN];       // [k][n]
    __shared__ float wgs[BN][M_EXP];
    __shared__ float actS[BM][BN + 1];

    const int tid = threadIdx.x;
    const int tx = tid & 15;              // 16 col groups of 4
    const int ty = tid >> 4;              // 16 row groups of 2
    const int m0 = blockIdx.x * BM;
    const int n0 = blockIdx.y * BN;

    // wg slab for this n-range: 64 rows x 16 = 256 float4, 1 per thread
    {
        const int r  = tid >> 2;
        const int c4 = (tid & 3) * 4;
        *reinterpret_cast<float4*>(&wgs[r][c4]) =
            *reinterpret_cast<const float4*>(wg + (size_t)(n0 + r) * M_EXP + c4);
    }

    // A-tile mapping: 32 rows x 64 k = 512 float4, 2/thread
    const int ar  = tid >> 4;             // rows ar, ar+16
    const int ak4 = (tid & 15) * 4;
    // W-tile mapping: 64 k x 64 n = 1024 float4, 4/thread
    const int wr0 = tid >> 4;             // k rows wr0, +16, +32, +48
    const int wc4 = (tid & 15) * 4;

    float4 pa0, pa1, pw0, pw1, pw2, pw3;

    // prologue: tile 0 -> LDS buf 0; tile 1 in flight
    LOADA(0); LOADW(0);
    STOREA(0); STOREW(0);
    LOADA(BK); LOADW(BK);
    __syncthreads();

    float acc[2][4] = {};
    int cur = 0;

    for (int t = 0; t < NITER; ++t) {
#pragma unroll
        for (int kk = 0; kk < BK; ++kk) {
            const float2 a = *reinterpret_cast<const float2*>(&As[cur][kk][ty * 2]);
            const float4 w = *reinterpret_cast<const float4*>(&Ws[cur][kk][tx * 4]);
            acc[0][0] = fmaf(a.x, w.x, acc[0][0]);
            acc[0][1] = fmaf(a.x, w.y, acc[0][1]);
            acc[0][2] = fmaf(a.x, w.z, acc[0][2]);
            acc[0][3] = fmaf(a.x, w.w, acc[0][3]);
            acc[1][0] = fmaf(a.y, w.x, acc[1][0]);
            acc[1][1] = fmaf(a.y, w.y, acc[1][1]);
            acc[1][2] = fmaf(a.y, w.z, acc[1][2]);
            acc[1][3] = fmaf(a.y, w.w, acc[1][3]);
        }
        if (t < NITER - 1) {
            const int nxt = cur ^ 1;
            STOREA(nxt); STOREW(nxt);
            if (t < NITER - 2) {
                const int k0 = (t + 2) * BK;
                LOADA(k0); LOADW(k0);
            }
            __syncthreads();
            cur = nxt;
        }
    }

    // epilogue: bias + exact GELU -> actS
#pragma unroll
    for (int i = 0; i < 2; ++i) {
        const int m = ty * 2 + i;
#pragma unroll
        for (int j = 0; j < 4; ++j) {
            const int n = tx * 4 + j;
            const float v = acc[i][j] + bias[n0 + n];
            actS[m][n] = v * 0.5f * (1.0f + erff(v * 0.70710678118654752440f));
        }
    }
    __syncthreads();

    // partial logits: 32 rows x 16 experts = 512 values, 2 per thread
    const int pm = tid >> 3;              // 0..31
    const int pe = (tid & 7) * 2;         // 0,2,..,14
    float s0 = 0.0f, s1 = 0.0f;
#pragma unroll
    for (int n = 0; n < BN; ++n) {
        const float a = actS[pm][n];
        s0 = fmaf(a, wgs[n][pe], s0);
        s1 = fmaf(a, wgs[n][pe + 1], s1);
    }
    float* pr = part + ((size_t)blockIdx.y * BATCH + (m0 + pm)) * M_EXP + pe;
    pr[0] = s0;
    pr[1] = s1;
}

// ---------------------------------------------------------------------------
// Kernel 3: finalize — sum 28 partials (fixed order, deterministic),
// softmax over 16, top-2 routing. One thread per batch row.
// ---------------------------------------------------------------------------
__global__ __launch_bounds__(64) void finalize_kernel(const float* __restrict__ part,
                                                      float* __restrict__ out) {
    const int b = blockIdx.x * 64 + threadIdx.x;   // 0..255

    float l[M_EXP];
#pragma unroll
    for (int m = 0; m < M_EXP; ++m) l[m] = 0.0f;

    for (int nb = 0; nb < NITER; ++nb) {
        const float4* pr = reinterpret_cast<const float4*>(part + ((size_t)nb * BATCH + b) * M_EXP);
#pragma unroll
        for (int q = 0; q < 4; ++q) {
            const float4 v = pr[q];
            l[q * 4 + 0] += v.x;
            l[q * 4 + 1] += v.y;
            l[q * 4 + 2] += v.z;
            l[q * 4 + 3] += v.w;
        }
    }

    // softmax over all 16 (probs_for_mi)
    float mx = l[0];
#pragma unroll
    for (int m = 1; m < M_EXP; ++m) mx = fmaxf(mx, l[m]);
    float e[M_EXP], s = 0.0f;
#pragma unroll
    for (int m = 0; m < M_EXP; ++m) { e[m] = expf(l[m] - mx); s += e[m]; }
    const float inv = 1.0f / s;
#pragma unroll
    for (int m = 0; m < M_EXP; ++m) out[OUT_PROBS + b * M_EXP + m] = e[m] * inv;

    // top-2, earliest-index tie-break (matches lax.top_k)
    int i0 = 0; float v0 = l[0];
#pragma unroll
    for (int m = 1; m < M_EXP; ++m) if (l[m] > v0) { v0 = l[m]; i0 = m; }
    int i1 = -1; float v1 = -INFINITY;
#pragma unroll
    for (int m = 0; m < M_EXP; ++m) if (m != i0 && l[m] > v1) { v1 = l[m]; i1 = m; }

    const float t = expf(v1 - v0);
    const float g0 = 1.0f / (1.0f + t);
    const float g1 = t * g0;

#pragma unroll
    for (int m = 0; m < M_EXP; ++m) out[OUT_GATES + b * M_EXP + m] = 0.0f;
    out[OUT_GATES + b * M_EXP + i0] = g0;
    out[OUT_GATES + b * M_EXP + i1] = g1;

    out[OUT_IDX + b * 2 + 0] = (float)i0;
    out[OUT_IDX + b * 2 + 1] = (float)i1;

    if (b == 0) out[OUT_LOSS] = 0.0f;
}

// ---------------------------------------------------------------------------
extern "C" void kernel_launch(void* const* d_in, const int* in_sizes, int n_in,
                              void* d_out, int out_size, void* d_ws, size_t ws_size,
                              hipStream_t stream) {
    const float* x        = (const float*)d_in[0];
    const float* degraded = (const float*)d_in[1];
    const float* w_fusion = (const float*)d_in[2];
    const float* b_fusion = (const float*)d_in[3];
    const float* w_gate   = (const float*)d_in[4];
    float* out = (float*)d_out;

    float* fused = (float*)d_ws;                         // 256*1792 f32 = 1.8 MB
    float* part  = fused + (size_t)BATCH * FDIM;         // 28*256*16 f32 = 459 KB

    // 1) pool + degraded copy
    pool_copy_kernel<<<NBLK_POOL + NBLK_COPY, 256, 0, stream>>>(x, degraded, fused);

    // 2) fusion GEMM + gelu + gate partials: grid (8, 28)
    gemm_gate_kernel<<<dim3(BATCH / BM, FDIM / BN), 256, 0, stream>>>(fused, w_fusion, b_fusion, w_gate, part);

    // 3) finalize: softmax + top-2, one thread per row
    finalize_kernel<<<BATCH / 64, 64, 0, stream>>>(part, out);
}